// Round 1
// baseline (869.080 us; speedup 1.0000x reference)
//
#include <hip/hip_runtime.h>
#include <stdint.h>
#include <stddef.h>

// MLA prefill: B=2,S=2048,D=2048,H=16,DH=128,DR=64,DCKV=512,DCQ=1536
#define BB 2
#define SS 2048
#define DD 2048
#define HH 16
#define DHH 128
#define DRR 64
#define DCKV 512
#define DCQ 1536

typedef __attribute__((ext_vector_type(8))) short short8;
typedef __attribute__((ext_vector_type(4))) short short4v;
typedef __attribute__((ext_vector_type(4))) float f32x4;

__device__ __forceinline__ short f2bf(float x) {
  unsigned u = __float_as_uint(x);
  u += 0x7fffu + ((u >> 16) & 1u);   // RNE
  return (short)(u >> 16);
}
__device__ __forceinline__ float bf2f(short s) {
  return __uint_as_float(((unsigned)(unsigned short)s) << 16);
}

// ---------------- cast fp32 -> bf16, x4 vectorized ----------------
__global__ __launch_bounds__(256) void cast_bf16_kernel(const float* __restrict__ in,
                                                        short* __restrict__ out, int n4) {
  int i = blockIdx.x * 256 + threadIdx.x;
  if (i >= n4) return;
  f32x4 f = ((const f32x4*)in)[i];
  short4v o;
  o[0] = f2bf(f[0]); o[1] = f2bf(f[1]); o[2] = f2bf(f[2]); o[3] = f2bf(f[3]);
  ((short4v*)out)[i] = o;
}

// ---------------- C[M,N] = A[M,K] @ B[N,K]^T + bias ----------------
// bf16 inputs, fp32 accumulate; 128x128 tile, BK=32, 4 waves (2x2 of 64x64).
// LDS XOR-swizzle: slot(row,q) = row*4 + (q ^ ((row>>1)&3)) -> conflict-free b128 reads.
template<bool OUT_F32>
__global__ __launch_bounds__(256) void gemm_bt(const short* __restrict__ A, const short* __restrict__ Bm,
                                               const float* __restrict__ bias, void* __restrict__ Cout,
                                               int M, int N, int K) {
  __shared__ short sA[128 * 32];
  __shared__ short sB[128 * 32];
  const int tid = threadIdx.x;
  const int w = tid >> 6, L = tid & 63, quad = L >> 4, lc = L & 15;
  const int wm = w >> 1, wn = w & 1;
  const int tm = blockIdx.x * 128, tn = blockIdx.y * 128;
  f32x4 acc[4][4] = {};
  const int nk = K >> 5;
  for (int kt = 0; kt < nk; ++kt) {
    const int k0 = kt << 5;
    __syncthreads();
#pragma unroll
    for (int i = 0; i < 2; ++i) {
      int g = i * 256 + tid;
      int r = g >> 2, q = g & 3;
      int slot = (g & ~3) | (q ^ ((r >> 1) & 3));
      short8 va = *(const short8*)(A + (size_t)(tm + r) * K + k0 + q * 8);
      *(short8*)&sA[slot * 8] = va;
      short8 vb = *(const short8*)(Bm + (size_t)(tn + r) * K + k0 + q * 8);
      *(short8*)&sB[slot * 8] = vb;
    }
    __syncthreads();
    short8 af[4], bfr[4];
#pragma unroll
    for (int ms = 0; ms < 4; ++ms) {
      int rr = wm * 64 + ms * 16 + lc;
      af[ms] = *(const short8*)&sA[(rr * 4 + (quad ^ ((rr >> 1) & 3))) * 8];
    }
#pragma unroll
    for (int ns = 0; ns < 4; ++ns) {
      int rr = wn * 64 + ns * 16 + lc;
      bfr[ns] = *(const short8*)&sB[(rr * 4 + (quad ^ ((rr >> 1) & 3))) * 8];
    }
#pragma unroll
    for (int ms = 0; ms < 4; ++ms)
#pragma unroll
      for (int ns = 0; ns < 4; ++ns)
        acc[ms][ns] = __builtin_amdgcn_mfma_f32_16x16x32_bf16(af[ms], bfr[ns], acc[ms][ns], 0, 0, 0);
  }
  // epilogue: C row = quad*4+reg, col = lane&15 (verified m89/m91 layout)
#pragma unroll
  for (int ms = 0; ms < 4; ++ms) {
    int row = tm + wm * 64 + ms * 16 + quad * 4;
#pragma unroll
    for (int ns = 0; ns < 4; ++ns) {
      int col = tn + wn * 64 + ns * 16 + lc;
      float bv = bias[col];
#pragma unroll
      for (int r = 0; r < 4; ++r) {
        float vv = acc[ms][ns][r] + bv;
        if (OUT_F32) ((float*)Cout)[(size_t)(row + r) * N + col] = vv;
        else         ((short*)Cout)[(size_t)(row + r) * N + col] = f2bf(vv);
      }
    }
  }
}

// ------------- copy content part into q_full/k_full [B,H,S,192] -------------
__global__ __launch_bounds__(256) void concat_cnt_kernel(const short* __restrict__ cnt,
                                                         short* __restrict__ full) {
  int idx = blockIdx.x * 256 + threadIdx.x;  // B*S*H*16 threads, 8 elems each
  int c = idx & 15, h = (idx >> 4) & 15, s = (idx >> 8) & 2047, b = idx >> 19;
  short8 v = *(const short8*)(cnt + ((size_t)(b * SS + s)) * 2048 + h * 128 + c * 8);
  *(short8*)(full + (((size_t)(b * HH + h)) * SS + s) * 192 + c * 8) = v;
}

// ------------- RoPE (rotate-half, tiled cos/sin) into full[...,128:192] -------------
__global__ __launch_bounds__(256) void rope_kernel(const short* __restrict__ rin,
                                                   short* __restrict__ full) {
  int idx = blockIdx.x * 256 + threadIdx.x;  // B*S*H*32 threads
  int i = idx & 31, h = (idx >> 5) & 15, s = (idx >> 9) & 2047, b = idx >> 20;
  const short* base = rin + ((size_t)(b * SS + s)) * (HH * DRR) + h * DRR;
  float t1 = bf2f(base[i]), t2 = bf2f(base[i + 32]);
  float invf = expf(-9.210340371976184f * (float)i * (1.0f / 32.0f));  // 10000^(-i/32)
  float ang = (float)s * invf;
  float c = cosf(ang), sn = sinf(ang);
  short* ob = full + (((size_t)(b * HH + h)) * SS + s) * 192 + 128;
  ob[i]      = f2bf(t1 * c - t2 * sn);
  ob[i + 32] = f2bf(t1 * sn + t2 * c);
}

// ------------- V [B,S,H*DH] -> Vt [B,H,DH,S] (keys contiguous for PV B-frags) -------------
__global__ __launch_bounds__(256) void transpose_v_kernel(const short* __restrict__ v,
                                                          short* __restrict__ vt) {
  int idx = blockIdx.x * 256 + threadIdx.x;  // B*H*DH*S threads
  int s = idx & 2047, d = (idx >> 11) & 127, h = (idx >> 18) & 15, b = idx >> 22;
  vt[idx] = v[((size_t)(b * SS + s)) * 2048 + h * 128 + d];
}

__device__ __forceinline__ float quad_max(float v) {
  v = fmaxf(v, __shfl_xor(v, 1));
  v = fmaxf(v, __shfl_xor(v, 2));
  v = fmaxf(v, __shfl_xor(v, 4));
  v = fmaxf(v, __shfl_xor(v, 8));
  return v;
}
__device__ __forceinline__ float quad_sum(float v) {
  v += __shfl_xor(v, 1); v += __shfl_xor(v, 2);
  v += __shfl_xor(v, 4); v += __shfl_xor(v, 8);
  return v;
}

// ------------- flash attention: Q-tile 128, K-tile 128, online softmax -------------
// grid (S/128, B*H); 4 waves, each owns 32 q-rows. P goes C-layout -> LDS -> A-layout.
__global__ __launch_bounds__(256, 2) void mla_flash_kernel(const short* __restrict__ Qf,
                                                           const short* __restrict__ Kf,
                                                           const short* __restrict__ Vt,
                                                           short* __restrict__ attn) {
  const int qt = blockIdx.x;
  const int h = blockIdx.y & 15, b = blockIdx.y >> 4;
  const int tid = threadIdx.x, w = tid >> 6, L = tid & 63, quad = L >> 4, lc = L & 15;
  __shared__ __align__(16) short Plds[4][32][136];  // +8 pad: stride 272B = 17*16B -> no conflicts

  const short* Qb = Qf + ((size_t)(b * HH + h)) * SS * 192;
  const short* Kb = Kf + ((size_t)(b * HH + h)) * SS * 192;
  const short* Vb = Vt + ((size_t)(b * HH + h)) * DHH * SS;

  const int qrow0 = qt * 128 + w * 32;
  short8 qa[2][6];
#pragma unroll
  for (int ms = 0; ms < 2; ++ms)
#pragma unroll
    for (int kk = 0; kk < 6; ++kk)
      qa[ms][kk] = *(const short8*)(Qb + (size_t)(qrow0 + ms * 16 + lc) * 192 + kk * 32 + quad * 8);

  f32x4 O[2][8] = {};
  float mrow[2][4], lrow[2][4];
#pragma unroll
  for (int ms = 0; ms < 2; ++ms)
#pragma unroll
    for (int r = 0; r < 4; ++r) { mrow[ms][r] = -1e30f; lrow[ms][r] = 0.f; }

  for (int kt = 0; kt <= qt; ++kt) {
    f32x4 sc[2][8] = {};
#pragma unroll
    for (int kk = 0; kk < 6; ++kk) {
      short8 kb[8];
#pragma unroll
      for (int ns = 0; ns < 8; ++ns)
        kb[ns] = *(const short8*)(Kb + (size_t)(kt * 128 + ns * 16 + lc) * 192 + kk * 32 + quad * 8);
#pragma unroll
      for (int ms = 0; ms < 2; ++ms)
#pragma unroll
        for (int ns = 0; ns < 8; ++ns)
          sc[ms][ns] = __builtin_amdgcn_mfma_f32_16x16x32_bf16(qa[ms][kk], kb[ns], sc[ms][ns], 0, 0, 0);
    }
    const float scale = 0.07216878364870322f;  // 1/sqrt(192)
    const bool diag = (kt == qt);
#pragma unroll
    for (int ms = 0; ms < 2; ++ms)
#pragma unroll
      for (int ns = 0; ns < 8; ++ns)
#pragma unroll
        for (int r = 0; r < 4; ++r) {
          float vv = sc[ms][ns][r] * scale;
          if (diag && (ns * 16 + lc > w * 32 + ms * 16 + quad * 4 + r)) vv = -1e30f;
          sc[ms][ns][r] = vv;
        }
    // online softmax; row r lives in the 16 lanes of this quad
#pragma unroll
    for (int ms = 0; ms < 2; ++ms)
#pragma unroll
      for (int r = 0; r < 4; ++r) {
        float mx = sc[ms][0][r];
#pragma unroll
        for (int ns = 1; ns < 8; ++ns) mx = fmaxf(mx, sc[ms][ns][r]);
        mx = quad_max(mx);
        float mnew = fmaxf(mrow[ms][r], mx);
        float alpha = __expf(mrow[ms][r] - mnew);
        mrow[ms][r] = mnew;
        float ps = 0.f;
#pragma unroll
        for (int ns = 0; ns < 8; ++ns) {
          float p = __expf(sc[ms][ns][r] - mnew);
          sc[ms][ns][r] = p;
          ps += p;
        }
        ps = quad_sum(ps);
        lrow[ms][r] = lrow[ms][r] * alpha + ps;
#pragma unroll
        for (int n = 0; n < 8; ++n) O[ms][n][r] *= alpha;
      }
    // P (bf16) C-layout -> LDS
#pragma unroll
    for (int ms = 0; ms < 2; ++ms)
#pragma unroll
      for (int ns = 0; ns < 8; ++ns)
#pragma unroll
        for (int r = 0; r < 4; ++r)
          Plds[w][ms * 16 + quad * 4 + r][ns * 16 + lc] = f2bf(sc[ms][ns][r]);
    __syncthreads();  // conservative lgkm ordering for cross-lane LDS visibility
    // PV: A = P (A-layout from LDS), B = Vt (8 contiguous keys per lane)
#pragma unroll
    for (int kk2 = 0; kk2 < 4; ++kk2) {
      short8 pa[2];
      pa[0] = *(const short8*)&Plds[w][lc][kk2 * 32 + quad * 8];
      pa[1] = *(const short8*)&Plds[w][16 + lc][kk2 * 32 + quad * 8];
      short8 vb[8];
#pragma unroll
      for (int n = 0; n < 8; ++n)
        vb[n] = *(const short8*)(Vb + (size_t)(n * 16 + lc) * SS + kt * 128 + kk2 * 32 + quad * 8);
#pragma unroll
      for (int ms = 0; ms < 2; ++ms)
#pragma unroll
        for (int n = 0; n < 8; ++n)
          O[ms][n] = __builtin_amdgcn_mfma_f32_16x16x32_bf16(pa[ms], vb[n], O[ms][n], 0, 0, 0);
    }
    __syncthreads();
  }
  // epilogue: O / l -> attn [B,S,H*DH] bf16
#pragma unroll
  for (int ms = 0; ms < 2; ++ms)
#pragma unroll
    for (int r = 0; r < 4; ++r) {
      float inv = 1.0f / lrow[ms][r];
      int srow = qt * 128 + w * 32 + ms * 16 + quad * 4 + r;
      short* dst = attn + ((size_t)b * SS + srow) * 2048 + h * 128;
#pragma unroll
      for (int n = 0; n < 8; ++n)
        dst[n * 16 + lc] = f2bf(O[ms][n][r] * inv);
    }
}

extern "C" void kernel_launch(void* const* d_in, const int* in_sizes, int n_in,
                              void* d_out, int out_size, void* d_ws, size_t ws_size,
                              hipStream_t stream) {
  const float* x   = (const float*)d_in[0];
  const float* Wkd = (const float*)d_in[1];
  const float* bkd = (const float*)d_in[2];
  const float* Wqd = (const float*)d_in[3];
  const float* bqd = (const float*)d_in[4];
  const float* Wku = (const float*)d_in[5];
  const float* bku = (const float*)d_in[6];
  const float* Wvu = (const float*)d_in[7];
  const float* bvu = (const float*)d_in[8];
  const float* Wqu = (const float*)d_in[9];
  const float* bqu = (const float*)d_in[10];
  const float* Wkr = (const float*)d_in[11];
  const float* bkr = (const float*)d_in[12];
  const float* Wqr = (const float*)d_in[13];
  const float* bqr = (const float*)d_in[14];
  const float* Wo  = (const float*)d_in[15];
  const float* bo  = (const float*)d_in[16];

  char* ws = (char*)d_ws;
  size_t off = 0;
  auto alloc = [&](size_t elems) -> short* {
    short* p = (short*)(ws + off);
    off += elems * sizeof(short);
    off = (off + 255) & ~(size_t)255;
    return p;
  };
  const int MS = BB * SS;  // 4096 rows for all projection GEMMs
  short* xb    = alloc((size_t)MS * DD);
  short* wkdb  = alloc((size_t)DCKV * DD);
  short* wqdb  = alloc((size_t)DCQ * DD);
  short* wkub  = alloc((size_t)HH * DHH * DCKV);
  short* wvub  = alloc((size_t)HH * DHH * DCKV);
  short* wqub  = alloc((size_t)HH * DHH * DCQ);
  short* wkrb  = alloc((size_t)HH * DRR * DD);
  short* wqrb  = alloc((size_t)HH * DRR * DCQ);
  short* wob   = alloc((size_t)DD * HH * DHH);
  short* kvc   = alloc((size_t)MS * DCKV);
  short* qc    = alloc((size_t)MS * DCQ);
  short* kcnt  = alloc((size_t)MS * HH * DHH);
  short* vbuf  = alloc((size_t)MS * HH * DHH);
  short* qcnt  = alloc((size_t)MS * HH * DHH);
  short* krb   = alloc((size_t)MS * HH * DRR);
  short* qrb   = alloc((size_t)MS * HH * DRR);
  short* qfull = alloc((size_t)BB * HH * SS * 192);
  short* kfull = alloc((size_t)BB * HH * SS * 192);
  short* vt    = alloc((size_t)BB * HH * DHH * SS);
  short* attn  = alloc((size_t)MS * HH * DHH);
  if (off > ws_size) return;  // workspace too small: fail visibly, don't corrupt

  auto cast = [&](const float* src, short* dst, size_t n) {
    int n4 = (int)(n >> 2);
    cast_bf16_kernel<<<dim3((unsigned)((n4 + 255) / 256)), dim3(256), 0, stream>>>(src, dst, n4);
  };
  cast(x,   xb,   (size_t)MS * DD);
  cast(Wkd, wkdb, (size_t)DCKV * DD);
  cast(Wqd, wqdb, (size_t)DCQ * DD);
  cast(Wku, wkub, (size_t)HH * DHH * DCKV);
  cast(Wvu, wvub, (size_t)HH * DHH * DCKV);
  cast(Wqu, wqub, (size_t)HH * DHH * DCQ);
  cast(Wkr, wkrb, (size_t)HH * DRR * DD);
  cast(Wqr, wqrb, (size_t)HH * DRR * DCQ);
  cast(Wo,  wob,  (size_t)DD * HH * DHH);

  dim3 blk(256);
  gemm_bt<false><<<dim3(MS / 128, DCKV / 128), blk, 0, stream>>>(xb,  wkdb, bkd, kvc,  MS, DCKV, DD);
  gemm_bt<false><<<dim3(MS / 128, DCQ  / 128), blk, 0, stream>>>(xb,  wqdb, bqd, qc,   MS, DCQ,  DD);
  gemm_bt<false><<<dim3(MS / 128, 2048 / 128), blk, 0, stream>>>(kvc, wkub, bku, kcnt, MS, 2048, DCKV);
  gemm_bt<false><<<dim3(MS / 128, 2048 / 128), blk, 0, stream>>>(kvc, wvub, bvu, vbuf, MS, 2048, DCKV);
  gemm_bt<false><<<dim3(MS / 128, 2048 / 128), blk, 0, stream>>>(qc,  wqub, bqu, qcnt, MS, 2048, DCQ);
  gemm_bt<false><<<dim3(MS / 128, 1024 / 128), blk, 0, stream>>>(xb,  wkrb, bkr, krb,  MS, 1024, DD);
  gemm_bt<false><<<dim3(MS / 128, 1024 / 128), blk, 0, stream>>>(qc,  wqrb, bqr, qrb,  MS, 1024, DCQ);

  concat_cnt_kernel<<<dim3(BB * SS * HH * 16 / 256), blk, 0, stream>>>(qcnt, qfull);
  concat_cnt_kernel<<<dim3(BB * SS * HH * 16 / 256), blk, 0, stream>>>(kcnt, kfull);
  rope_kernel<<<dim3(BB * SS * HH * 32 / 256), blk, 0, stream>>>(qrb, qfull);
  rope_kernel<<<dim3(BB * SS * HH * 32 / 256), blk, 0, stream>>>(krb, kfull);
  transpose_v_kernel<<<dim3(BB * HH * DHH * SS / 256), blk, 0, stream>>>(vbuf, vt);

  mla_flash_kernel<<<dim3(SS / 128, BB * HH), blk, 0, stream>>>(qfull, kfull, vt, attn);

  gemm_bt<true><<<dim3(MS / 128, DD / 128), blk, 0, stream>>>(attn, wob, bo, d_out, MS, DD, DD);
}

// Round 3
// 793.701 us; speedup vs baseline: 1.0950x; 1.0950x over previous
//
#include <hip/hip_runtime.h>
#include <stdint.h>
#include <stddef.h>

// MLA prefill: B=2,S=2048,D=2048,H=16,DH=128,DR=64,DCKV=512,DCQ=1536
#define BB 2
#define SS 2048
#define DD 2048
#define HH 16
#define DHH 128
#define DRR 64
#define DCKV 512
#define DCQ 1536

typedef __attribute__((ext_vector_type(8))) short short8;
typedef __attribute__((ext_vector_type(4))) short short4v;
typedef __attribute__((ext_vector_type(4))) float f32x4;

__device__ __forceinline__ short f2bf(float x) {
  unsigned u = __float_as_uint(x);
  u += 0x7fffu + ((u >> 16) & 1u);   // RNE
  return (short)(u >> 16);
}
__device__ __forceinline__ float bf2f(short s) {
  return __uint_as_float(((unsigned)(unsigned short)s) << 16);
}

// ---------------- cast fp32 -> bf16, x4 vectorized ----------------
__global__ __launch_bounds__(256) void cast_bf16_kernel(const float* __restrict__ in,
                                                        short* __restrict__ out, int n4) {
  int i = blockIdx.x * 256 + threadIdx.x;
  if (i >= n4) return;
  f32x4 f = ((const f32x4*)in)[i];
  short4v o;
  o[0] = f2bf(f[0]); o[1] = f2bf(f[1]); o[2] = f2bf(f[2]); o[3] = f2bf(f[3]);
  ((short4v*)out)[i] = o;
}

// ---------------- C[M,N] = A[M,K] @ B[N,K]^T + bias ----------------
// R1-proven version: register-staged LDS, 128x128 tile, BK=32, 4 waves.
// LDS XOR-swizzle: slot(row,q) = row*4 + (q ^ ((row>>1)&3)) -> conflict-free b128 reads.
template<bool OUT_F32>
__global__ __launch_bounds__(256) void gemm_bt(const short* __restrict__ A, const short* __restrict__ Bm,
                                               const float* __restrict__ bias, void* __restrict__ Cout,
                                               int M, int N, int K) {
  __shared__ short sA[128 * 32];
  __shared__ short sB[128 * 32];
  const int tid = threadIdx.x;
  const int w = tid >> 6, L = tid & 63, quad = L >> 4, lc = L & 15;
  const int wm = w >> 1, wn = w & 1;
  const int tm = blockIdx.x * 128, tn = blockIdx.y * 128;
  f32x4 acc[4][4] = {};
  const int nk = K >> 5;
  for (int kt = 0; kt < nk; ++kt) {
    const int k0 = kt << 5;
    __syncthreads();
#pragma unroll
    for (int i = 0; i < 2; ++i) {
      int g = i * 256 + tid;
      int r = g >> 2, q = g & 3;
      int slot = (g & ~3) | (q ^ ((r >> 1) & 3));
      short8 va = *(const short8*)(A + (size_t)(tm + r) * K + k0 + q * 8);
      *(short8*)&sA[slot * 8] = va;
      short8 vb = *(const short8*)(Bm + (size_t)(tn + r) * K + k0 + q * 8);
      *(short8*)&sB[slot * 8] = vb;
    }
    __syncthreads();
    short8 af[4], bfr[4];
#pragma unroll
    for (int ms = 0; ms < 4; ++ms) {
      int rr = wm * 64 + ms * 16 + lc;
      af[ms] = *(const short8*)&sA[(rr * 4 + (quad ^ ((rr >> 1) & 3))) * 8];
    }
#pragma unroll
    for (int ns = 0; ns < 4; ++ns) {
      int rr = wn * 64 + ns * 16 + lc;
      bfr[ns] = *(const short8*)&sB[(rr * 4 + (quad ^ ((rr >> 1) & 3))) * 8];
    }
#pragma unroll
    for (int ms = 0; ms < 4; ++ms)
#pragma unroll
      for (int ns = 0; ns < 4; ++ns)
        acc[ms][ns] = __builtin_amdgcn_mfma_f32_16x16x32_bf16(af[ms], bfr[ns], acc[ms][ns], 0, 0, 0);
  }
  // epilogue: C row = quad*4+reg, col = lane&15 (verified m89/m91 layout)
#pragma unroll
  for (int ms = 0; ms < 4; ++ms) {
    int row = tm + wm * 64 + ms * 16 + quad * 4;
#pragma unroll
    for (int ns = 0; ns < 4; ++ns) {
      int col = tn + wn * 64 + ns * 16 + lc;
      float bv = bias[col];
#pragma unroll
      for (int r = 0; r < 4; ++r) {
        float vv = acc[ms][ns][r] + bv;
        if (OUT_F32) ((float*)Cout)[(size_t)(row + r) * N + col] = vv;
        else         ((short*)Cout)[(size_t)(row + r) * N + col] = f2bf(vv);
      }
    }
  }
}

// ------------- copy content part into q_full/k_full [B,H,S,192] -------------
__global__ __launch_bounds__(256) void concat_cnt_kernel(const short* __restrict__ cnt,
                                                         short* __restrict__ full) {
  int idx = blockIdx.x * 256 + threadIdx.x;  // B*S*H*16 threads, 8 elems each
  int c = idx & 15, h = (idx >> 4) & 15, s = (idx >> 8) & 2047, b = idx >> 19;
  short8 v = *(const short8*)(cnt + ((size_t)(b * SS + s)) * 2048 + h * 128 + c * 8);
  *(short8*)(full + (((size_t)(b * HH + h)) * SS + s) * 192 + c * 8) = v;
}

// ------------- RoPE (rotate-half, tiled cos/sin) into full[...,128:192] -------------
__global__ __launch_bounds__(256) void rope_kernel(const short* __restrict__ rin,
                                                   short* __restrict__ full) {
  int idx = blockIdx.x * 256 + threadIdx.x;  // B*S*H*32 threads
  int i = idx & 31, h = (idx >> 5) & 15, s = (idx >> 9) & 2047, b = idx >> 20;
  const short* base = rin + ((size_t)(b * SS + s)) * (HH * DRR) + h * DRR;
  float t1 = bf2f(base[i]), t2 = bf2f(base[i + 32]);
  float invf = expf(-9.210340371976184f * (float)i * (1.0f / 32.0f));  // 10000^(-i/32)
  float ang = (float)s * invf;
  float c = cosf(ang), sn = sinf(ang);
  short* ob = full + (((size_t)(b * HH + h)) * SS + s) * 192 + 128;
  ob[i]      = f2bf(t1 * c - t2 * sn);
  ob[i + 32] = f2bf(t1 * sn + t2 * c);
}

// ------------- V [B,S,H*DH] -> Vt [B,H,DH,S] (keys contiguous for PV B-frags) -------------
__global__ __launch_bounds__(256) void transpose_v_kernel(const short* __restrict__ v,
                                                          short* __restrict__ vt) {
  int idx = blockIdx.x * 256 + threadIdx.x;  // B*H*DH*S threads
  int s = idx & 2047, d = (idx >> 11) & 127, h = (idx >> 18) & 15, b = idx >> 22;
  vt[idx] = v[((size_t)(b * SS + s)) * 2048 + h * 128 + d];
}

__device__ __forceinline__ float quad_max(float v) {
  v = fmaxf(v, __shfl_xor(v, 1));
  v = fmaxf(v, __shfl_xor(v, 2));
  v = fmaxf(v, __shfl_xor(v, 4));
  v = fmaxf(v, __shfl_xor(v, 8));
  return v;
}
__device__ __forceinline__ float quad_sum(float v) {
  v += __shfl_xor(v, 1); v += __shfl_xor(v, 2);
  v += __shfl_xor(v, 4); v += __shfl_xor(v, 8);
  return v;
}

// ------------- flash attention: Q-tile 128, K-tile 128, online softmax -------------
// grid (16, B*H), heavy-first (qt = 15-bx).
// K-tile staged cooperatively into 48KB LDS via plain loads + ds_write_b128
// (NOT global_load_lds — R2 crash isolation). Segment-major layout
// sK[seg][128][32] with the R1-gemm XOR swizzle. P buffer (128x136 bf16,
// wave-private rows) unioned at sK offset 0; 4 barriers/iter.
__global__ __launch_bounds__(256, 2) void mla_flash_kernel(const short* __restrict__ Qf,
                                                           const short* __restrict__ Kf,
                                                           const short* __restrict__ Vt,
                                                           short* __restrict__ attn) {
  const int qt = (int)(gridDim.x - 1 - blockIdx.x);  // heavy blocks dispatch first
  const int h = blockIdx.y & 15, b = blockIdx.y >> 4;
  const int tid = threadIdx.x, w = tid >> 6, L = tid & 63, quad = L >> 4, lc = L & 15;
  __shared__ __align__(16) short sK[6 * 128 * 32];  // 48KB; P unioned at offset 0
  short* Pf = sK;                                   // [128][136] bf16 = 34.8KB

  const short* Qb = Qf + ((size_t)(b * HH + h)) * SS * 192;
  const short* Kb = Kf + ((size_t)(b * HH + h)) * SS * 192;
  const short* Vb = Vt + ((size_t)(b * HH + h)) * DHH * SS;

  const int qrow0 = qt * 128 + w * 32;
  short8 qa[2][6];
#pragma unroll
  for (int ms = 0; ms < 2; ++ms)
#pragma unroll
    for (int kk = 0; kk < 6; ++kk)
      qa[ms][kk] = *(const short8*)(Qb + (size_t)(qrow0 + ms * 16 + lc) * 192 + kk * 32 + quad * 8);

  f32x4 O[2][8] = {};
  float mrow[2][4], lrow[2][4];
#pragma unroll
  for (int ms = 0; ms < 2; ++ms)
#pragma unroll
    for (int r = 0; r < 4; ++r) { mrow[ms][r] = -1e30f; lrow[ms][r] = 0.f; }

  for (int kt = 0; kt <= qt; ++kt) {
    __syncthreads();  // prior iter's P/sK LDS reads all done before overwrite
    // stage K-tile [kt*128, +128) x 192 into sK: 3072 16B chunks, 12/thread
#pragma unroll
    for (int i = 0; i < 12; ++i) {
      int idx = i * 256 + tid;
      int seg = idx >> 9, rem = idx & 511, row = rem >> 2, q = rem & 3;
      short8 v = *(const short8*)(Kb + (size_t)(kt * 128 + row) * 192 + seg * 32 + q * 8);
      int slot = row * 4 + (q ^ ((row >> 1) & 3));
      *(short8*)&sK[(seg * 512 + slot) * 8] = v;
    }
    __syncthreads();  // sK ready
    // QK^T: per wave 2 ms x 8 ns accs over 6 K-segments
    f32x4 sc[2][8] = {};
#pragma unroll
    for (int kk = 0; kk < 6; ++kk)
#pragma unroll
      for (int ns = 0; ns < 8; ++ns) {
        int rr = ns * 16 + lc;
        short8 kb = *(const short8*)&sK[(kk * 512 + rr * 4 + (quad ^ ((rr >> 1) & 3))) * 8];
        sc[0][ns] = __builtin_amdgcn_mfma_f32_16x16x32_bf16(qa[0][kk], kb, sc[0][ns], 0, 0, 0);
        sc[1][ns] = __builtin_amdgcn_mfma_f32_16x16x32_bf16(qa[1][kk], kb, sc[1][ns], 0, 0, 0);
      }
    const float scale = 0.07216878364870322f;  // 1/sqrt(192)
    const bool diag = (kt == qt);
#pragma unroll
    for (int ms = 0; ms < 2; ++ms)
#pragma unroll
      for (int ns = 0; ns < 8; ++ns)
#pragma unroll
        for (int r = 0; r < 4; ++r) {
          float vv = sc[ms][ns][r] * scale;
          if (diag && (ns * 16 + lc > w * 32 + ms * 16 + quad * 4 + r)) vv = -1e30f;
          sc[ms][ns][r] = vv;
        }
    // online softmax; row (ms, quad*4+r) lives in this quad's 16 lanes
#pragma unroll
    for (int ms = 0; ms < 2; ++ms)
#pragma unroll
      for (int r = 0; r < 4; ++r) {
        float mx = sc[ms][0][r];
#pragma unroll
        for (int ns = 1; ns < 8; ++ns) mx = fmaxf(mx, sc[ms][ns][r]);
        mx = quad_max(mx);
        float mnew = fmaxf(mrow[ms][r], mx);
        float alpha = __expf(mrow[ms][r] - mnew);
        mrow[ms][r] = mnew;
        float ps = 0.f;
#pragma unroll
        for (int ns = 0; ns < 8; ++ns) {
          float p = __expf(sc[ms][ns][r] - mnew);
          sc[ms][ns][r] = p;
          ps += p;
        }
        ps = quad_sum(ps);
        lrow[ms][r] = lrow[ms][r] * alpha + ps;
#pragma unroll
        for (int n = 0; n < 8; ++n) O[ms][n][r] *= alpha;
      }
    __syncthreads();  // all waves' QK sK-reads done before P overwrites region
    // P (bf16) C-layout -> LDS (wave-private rows)
#pragma unroll
    for (int ms = 0; ms < 2; ++ms)
#pragma unroll
      for (int ns = 0; ns < 8; ++ns)
#pragma unroll
        for (int r = 0; r < 4; ++r)
          Pf[(w * 32 + ms * 16 + quad * 4 + r) * 136 + ns * 16 + lc] = f2bf(sc[ms][ns][r]);
    __syncthreads();  // conservative (matches R1-proven semantics)
    // PV: A = P (own rows, A-layout), B = Vt (16 rows x 64B contiguous per wave)
#pragma unroll
    for (int kk2 = 0; kk2 < 4; ++kk2) {
      short8 pa[2];
      pa[0] = *(const short8*)&Pf[(w * 32 + lc) * 136 + kk2 * 32 + quad * 8];
      pa[1] = *(const short8*)&Pf[(w * 32 + 16 + lc) * 136 + kk2 * 32 + quad * 8];
      short8 vb[8];
#pragma unroll
      for (int n = 0; n < 8; ++n)
        vb[n] = *(const short8*)(Vb + (size_t)(n * 16 + lc) * SS + kt * 128 + kk2 * 32 + quad * 8);
#pragma unroll
      for (int ms = 0; ms < 2; ++ms)
#pragma unroll
        for (int n = 0; n < 8; ++n)
          O[ms][n] = __builtin_amdgcn_mfma_f32_16x16x32_bf16(pa[ms], vb[n], O[ms][n], 0, 0, 0);
    }
  }
  // epilogue: O / l -> attn [B,S,H*DH] bf16
#pragma unroll
  for (int ms = 0; ms < 2; ++ms)
#pragma unroll
    for (int r = 0; r < 4; ++r) {
      float inv = 1.0f / lrow[ms][r];
      int srow = qt * 128 + w * 32 + ms * 16 + quad * 4 + r;
      short* dst = attn + ((size_t)b * SS + srow) * 2048 + h * 128;
#pragma unroll
      for (int n = 0; n < 8; ++n)
        dst[n * 16 + lc] = f2bf(O[ms][n][r] * inv);
    }
}

extern "C" void kernel_launch(void* const* d_in, const int* in_sizes, int n_in,
                              void* d_out, int out_size, void* d_ws, size_t ws_size,
                              hipStream_t stream) {
  const float* x   = (const float*)d_in[0];
  const float* Wkd = (const float*)d_in[1];
  const float* bkd = (const float*)d_in[2];
  const float* Wqd = (const float*)d_in[3];
  const float* bqd = (const float*)d_in[4];
  const float* Wku = (const float*)d_in[5];
  const float* bku = (const float*)d_in[6];
  const float* Wvu = (const float*)d_in[7];
  const float* bvu = (const float*)d_in[8];
  const float* Wqu = (const float*)d_in[9];
  const float* bqu = (const float*)d_in[10];
  const float* Wkr = (const float*)d_in[11];
  const float* bkr = (const float*)d_in[12];
  const float* Wqr = (const float*)d_in[13];
  const float* bqr = (const float*)d_in[14];
  const float* Wo  = (const float*)d_in[15];
  const float* bo  = (const float*)d_in[16];

  char* ws = (char*)d_ws;
  size_t off = 0;
  auto alloc = [&](size_t elems) -> short* {
    short* p = (short*)(ws + off);
    off += elems * sizeof(short);
    off = (off + 255) & ~(size_t)255;
    return p;
  };
  const int MS = BB * SS;  // 4096 rows for all projection GEMMs
  short* xb    = alloc((size_t)MS * DD);
  short* wkdb  = alloc((size_t)DCKV * DD);
  short* wqdb  = alloc((size_t)DCQ * DD);
  short* wkub  = alloc((size_t)HH * DHH * DCKV);
  short* wvub  = alloc((size_t)HH * DHH * DCKV);
  short* wqub  = alloc((size_t)HH * DHH * DCQ);
  short* wkrb  = alloc((size_t)HH * DRR * DD);
  short* wqrb  = alloc((size_t)HH * DRR * DCQ);
  short* wob   = alloc((size_t)DD * HH * DHH);
  short* kvc   = alloc((size_t)MS * DCKV);
  short* qc    = alloc((size_t)MS * DCQ);
  short* kcnt  = alloc((size_t)MS * HH * DHH);
  short* vbuf  = alloc((size_t)MS * HH * DHH);
  short* qcnt  = alloc((size_t)MS * HH * DHH);
  short* krb   = alloc((size_t)MS * HH * DRR);
  short* qrb   = alloc((size_t)MS * HH * DRR);
  short* qfull = alloc((size_t)BB * HH * SS * 192);
  short* kfull = alloc((size_t)BB * HH * SS * 192);
  short* vt    = alloc((size_t)BB * HH * DHH * SS);
  short* attn  = alloc((size_t)MS * HH * DHH);
  if (off > ws_size) return;  // workspace too small: fail visibly, don't corrupt

  auto cast = [&](const float* src, short* dst, size_t n) {
    int n4 = (int)(n >> 2);
    cast_bf16_kernel<<<dim3((unsigned)((n4 + 255) / 256)), dim3(256), 0, stream>>>(src, dst, n4);
  };
  cast(x,   xb,   (size_t)MS * DD);
  cast(Wkd, wkdb, (size_t)DCKV * DD);
  cast(Wqd, wqdb, (size_t)DCQ * DD);
  cast(Wku, wkub, (size_t)HH * DHH * DCKV);
  cast(Wvu, wvub, (size_t)HH * DHH * DCKV);
  cast(Wqu, wqub, (size_t)HH * DHH * DCQ);
  cast(Wkr, wkrb, (size_t)HH * DRR * DD);
  cast(Wqr, wqrb, (size_t)HH * DRR * DCQ);
  cast(Wo,  wob,  (size_t)DD * HH * DHH);

  dim3 blk(256);
  gemm_bt<false><<<dim3(MS / 128, DCKV / 128), blk, 0, stream>>>(xb,  wkdb, bkd, kvc,  MS, DCKV, DD);
  gemm_bt<false><<<dim3(MS / 128, DCQ  / 128), blk, 0, stream>>>(xb,  wqdb, bqd, qc,   MS, DCQ,  DD);
  gemm_bt<false><<<dim3(MS / 128, 2048 / 128), blk, 0, stream>>>(kvc, wkub, bku, kcnt, MS, 2048, DCKV);
  gemm_bt<false><<<dim3(MS / 128, 2048 / 128), blk, 0, stream>>>(kvc, wvub, bvu, vbuf, MS, 2048, DCKV);
  gemm_bt<false><<<dim3(MS / 128, 2048 / 128), blk, 0, stream>>>(qc,  wqub, bqu, qcnt, MS, 2048, DCQ);
  gemm_bt<false><<<dim3(MS / 128, 1024 / 128), blk, 0, stream>>>(xb,  wkrb, bkr, krb,  MS, 1024, DD);
  gemm_bt<false><<<dim3(MS / 128, 1024 / 128), blk, 0, stream>>>(qc,  wqrb, bqr, qrb,  MS, 1024, DCQ);

  concat_cnt_kernel<<<dim3(BB * SS * HH * 16 / 256), blk, 0, stream>>>(qcnt, qfull);
  concat_cnt_kernel<<<dim3(BB * SS * HH * 16 / 256), blk, 0, stream>>>(kcnt, kfull);
  rope_kernel<<<dim3(BB * SS * HH * 32 / 256), blk, 0, stream>>>(qrb, qfull);
  rope_kernel<<<dim3(BB * SS * HH * 32 / 256), blk, 0, stream>>>(krb, kfull);
  transpose_v_kernel<<<dim3(BB * HH * DHH * SS / 256), blk, 0, stream>>>(vbuf, vt);

  mla_flash_kernel<<<dim3(SS / 128, BB * HH), blk, 0, stream>>>(qfull, kfull, vt, attn);

  gemm_bt<true><<<dim3(MS / 128, DD / 128), blk, 0, stream>>>(attn, wob, bo, d_out, MS, DD, DD);
}